// Round 4
// baseline (113.091 us; speedup 1.0000x reference)
//
#include <hip/hip_runtime.h>

// LIF integrate-fire-reset scan over T.
// inputs: [B=32, T=2048, N=1024] f32; thresh: [N] f32; out: [B, T, N] f32.
// One thread per (b, n) chain; chain elements stride N floats, consecutive
// threads -> consecutive addresses (coalesced 256B/wave per timestep).
//
// Memory-bound (512 MiB traffic, ~81 us roofline). Only 32768 threads total
// (2 waves/CU), so latency hiding must come from ILP: a double-buffered
// register pipeline of U timesteps keeps U loads in flight per thread
// (32768 * 32 * 4B = 4 MB in flight > ~2.5 MB BW*latency product).

constexpr int T_STEPS = 2048;
constexpr int N_COLS  = 1024;
constexpr int U       = 32;   // prefetch depth (register double-buffer)

__global__ __launch_bounds__(64, 1)
void lif_scan_kernel(const float* __restrict__ x,
                     const float* __restrict__ thresh,
                     float* __restrict__ out)
{
    const int gid = blockIdx.x * blockDim.x + threadIdx.x;   // 0 .. B*N-1
    const int b   = gid >> 10;          // / N_COLS
    const int n   = gid & (N_COLS - 1); // % N_COLS

    const float thr = thresh[n];

    const size_t base = (size_t)b * T_STEPS * N_COLS + n;
    const float* __restrict__ p = x   + base;
    float*       __restrict__ q = out + base;

    float cur[U];
    float nxt[U];

    // prologue: fill pipeline for t = 0..U-1
#pragma unroll
    for (int i = 0; i < U; ++i)
        cur[i] = __builtin_nontemporal_load(&p[(size_t)i * N_COLS]);

    float acc = 0.0f;

    for (int t0 = 0; t0 < T_STEPS; t0 += U) {
        // issue next chunk's loads first so they overlap this chunk's compute
        if (t0 + U < T_STEPS) {
#pragma unroll
            for (int i = 0; i < U; ++i)
                nxt[i] = __builtin_nontemporal_load(&p[(size_t)(t0 + U + i) * N_COLS]);
        }

        // integrate-fire-reset on the current chunk (all static indices ->
        // stays in registers)
#pragma unroll
        for (int i = 0; i < U; ++i) {
            acc += cur[i];
            const float o = (acc > thr) ? acc : 0.0f;
            acc -= o;   // reset fired neuron to 0
            __builtin_nontemporal_store(o, &q[(size_t)(t0 + i) * N_COLS]);
        }

        // rotate double buffer (register renaming, no scratch)
#pragma unroll
        for (int i = 0; i < U; ++i)
            cur[i] = nxt[i];
    }
}

extern "C" void kernel_launch(void* const* d_in, const int* in_sizes, int n_in,
                              void* d_out, int out_size, void* d_ws, size_t ws_size,
                              hipStream_t stream)
{
    const float* x      = (const float*)d_in[0];
    const float* thresh = (const float*)d_in[1];
    float*       out    = (float*)d_out;

    const int n_cols = in_sizes[1];                       // 1024
    const int chains = in_sizes[0] / T_STEPS / n_cols * n_cols * 1
                       ;                                  // B * N
    const int total  = in_sizes[0] / T_STEPS;             // B * N chains
    (void)chains; (void)out_size; (void)d_ws; (void)ws_size; (void)n_in;

    const int block = 64;
    const int grid  = (total + block - 1) / block;        // 512 blocks

    hipLaunchKernelGGL(lif_scan_kernel, dim3(grid), dim3(block), 0, stream,
                       x, thresh, out);
}